// Round 1
// baseline (122.806 us; speedup 1.0000x reference)
//
#include <hip/hip_runtime.h>

// TensorTrain: out[b] = first(x0) . M0(x1) . ... . M29(x30) . last(x31)
// with R=16, D=32, B=262144, selection bits in {0,1}.
//
// Strategy: meet-in-the-middle table precompute.
//   prefix p = bits x0..x15  (x0 = MSB)  -> V16[p] : R row-vector
//   suffix s = bits x16..x31 (x16 = MSB) -> W16[s] : R col-vector
//   out = V16[p] . W16[s]
// Tables built hierarchically: nibble (4-bit) products -> byte (8-bit)
// products -> 16-bit tables.  All fp32.

#define R 16
#define TT_D 32
#define BATCH 262144

// workspace layout, in floats
#define OFF_V4   0                      // 16 x 16      first . M0..M2   (x0..x3)
#define OFF_A    256                    // 16 x 256     M3..M6           (x4..x7)
#define OFF_B    (256 + 1*4096)         // 16 x 256     M7..M10          (x8..x11)
#define OFF_C    (256 + 2*4096)         // 16 x 256     M11..M14         (x12..x15)
#define OFF_Dm   (256 + 3*4096)         // 16 x 256     M15..M18         (x16..x19)
#define OFF_E    (256 + 4*4096)         // 16 x 256     M19..M22         (x20..x23)
#define OFF_F    (256 + 5*4096)         // 16 x 256     M23..M26         (x24..x27)
#define OFF_W4   (256 + 6*4096)         // 16 x 16      M27..M29 . last  (x28..x31)
#define OFF_V8   (OFF_W4 + 256)         // 256 x 16     V4 @ A
#define OFF_P8   (OFF_V8 + 4096)        // 256 x 256    B @ C
#define OFF_Q8   (OFF_P8 + 65536)       // 256 x 256    Dm @ E
#define OFF_W8   (OFF_Q8 + 65536)       // 256 x 16     F @ W4
#define OFF_V16  (OFF_W8 + 4096)        // 65536 x 16   V8 @ P8
#define OFF_W16  (OFF_V16 + 1048576)    // 65536 x 16   Q8 @ W8
#define WS_FLOATS (OFF_W16 + 1048576)   // 2,261,504 floats = ~9.05 MB

// ---------------------------------------------------------------------------
// Kernel A: nibble tables. 8 blocks (one per table) x 256 threads.
// Matrix tables (blocks 1..6): thread = (entry e, row r); computes row r of
// the 4-matrix product by chained row-matvec.
// Vector tables (block 0: prefix V4, block 7: suffix W4): 16 threads.
__global__ __launch_bounds__(256) void tt_nibble(const float* __restrict__ cf,
                                                 const float* __restrict__ cm,
                                                 const float* __restrict__ cl,
                                                 float* __restrict__ ws) {
    const int tbl = blockIdx.x;
    const int t = threadIdx.x;

    if (tbl >= 1 && tbl <= 6) {
        const int e = t >> 4, r = t & 15;
        const int base = 3 + (tbl - 1) * 4;   // first mid-core of this nibble
        const int b0 = (e >> 3) & 1, b1 = (e >> 2) & 1, b2 = (e >> 1) & 1, b3 = e & 1;
        float v[R], nv[R];
        const float* M0 = cm + base * 512;    // cores_mid[i][r][s][x] flat
        #pragma unroll
        for (int s2 = 0; s2 < R; s2++) v[s2] = M0[(r * 16 + s2) * 2 + b0];
        const int bits[3] = { b1, b2, b3 };
        for (int k = 1; k <= 3; k++) {
            const float* M = cm + (base + k) * 512;
            const int bb = bits[k - 1];
            #pragma unroll
            for (int s2 = 0; s2 < R; s2++) {
                float acc = 0.f;
                #pragma unroll
                for (int tt = 0; tt < R; tt++) acc += v[tt] * M[(tt * 16 + s2) * 2 + bb];
                nv[s2] = acc;
            }
            #pragma unroll
            for (int s2 = 0; s2 < R; s2++) v[s2] = nv[s2];
        }
        float* o = ws + OFF_A + (tbl - 1) * 4096 + e * 256 + r * 16;
        #pragma unroll
        for (int s2 = 0; s2 < R; s2++) o[s2] = v[s2];
    } else if (tbl == 0) {
        if (t < 16) {
            const int e = t;
            const int b0 = (e >> 3) & 1, b1 = (e >> 2) & 1, b2 = (e >> 1) & 1, b3 = e & 1;
            float v[R], nv[R];
            #pragma unroll
            for (int s2 = 0; s2 < R; s2++) v[s2] = cf[s2 * 2 + b0];   // first(x0)
            const int bits[3] = { b1, b2, b3 };
            for (int k = 1; k <= 3; k++) {
                const float* M = cm + (k - 1) * 512;                  // M0,M1,M2
                const int bb = bits[k - 1];
                #pragma unroll
                for (int s2 = 0; s2 < R; s2++) {
                    float acc = 0.f;
                    #pragma unroll
                    for (int tt = 0; tt < R; tt++) acc += v[tt] * M[(tt * 16 + s2) * 2 + bb];
                    nv[s2] = acc;
                }
                #pragma unroll
                for (int s2 = 0; s2 < R; s2++) v[s2] = nv[s2];
            }
            float* o = ws + OFF_V4 + e * 16;
            #pragma unroll
            for (int s2 = 0; s2 < R; s2++) o[s2] = v[s2];
        }
    } else { // tbl == 7: suffix nibble, column vectors
        if (t < 16) {
            const int e = t;
            const int b0 = (e >> 3) & 1, b1 = (e >> 2) & 1, b2 = (e >> 1) & 1, b3 = e & 1;
            float w[R], nw[R];
            #pragma unroll
            for (int r2 = 0; r2 < R; r2++) w[r2] = cl[r2 * 2 + b3];   // last(x31)
            const int cores[3] = { 29, 28, 27 };
            const int bits[3] = { b2, b1, b0 };
            for (int k = 0; k < 3; k++) {
                const float* M = cm + cores[k] * 512;
                const int bb = bits[k];
                #pragma unroll
                for (int r2 = 0; r2 < R; r2++) {
                    float acc = 0.f;
                    #pragma unroll
                    for (int tt = 0; tt < R; tt++) acc += M[(r2 * 16 + tt) * 2 + bb] * w[tt];
                    nw[r2] = acc;
                }
                #pragma unroll
                for (int r2 = 0; r2 < R; r2++) w[r2] = nw[r2];
            }
            float* o = ws + OFF_W4 + e * 16;
            #pragma unroll
            for (int r2 = 0; r2 < R; r2++) o[r2] = w[r2];
        }
    }
}

// ---------------------------------------------------------------------------
// Kernel B: byte tables. blocks 0..15: P8 rows; 16..31: Q8 rows;
// block 32: V8; block 33: W8.
__global__ __launch_bounds__(256) void tt_byte(float* __restrict__ ws) {
    const int g = blockIdx.x;
    const int t = threadIdx.x;
    if (g < 32) {
        const bool isP = (g < 16);
        const int idx = (isP ? g : g - 16) * 256 + t;  // 0..4095
        const int e = idx >> 4, r = idx & 15;
        const int h = e >> 4, l = e & 15;
        const float* Hm = ws + (isP ? OFF_B : OFF_Dm) + h * 256;
        const float* Lm = ws + (isP ? OFF_C : OFF_E) + l * 256;
        float hrow[R];
        #pragma unroll
        for (int k = 0; k < R; k++) hrow[k] = Hm[r * 16 + k];
        float outv[R];
        #pragma unroll
        for (int s2 = 0; s2 < R; s2++) outv[s2] = 0.f;
        #pragma unroll
        for (int k = 0; k < R; k++) {
            const float a = hrow[k];
            #pragma unroll
            for (int s2 = 0; s2 < R; s2++) outv[s2] += a * Lm[k * 16 + s2];
        }
        float* o = ws + (isP ? OFF_P8 : OFF_Q8) + e * 256 + r * 16;
        #pragma unroll
        for (int s2 = 0; s2 < R; s2++) o[s2] = outv[s2];
    } else if (g == 32) { // V8[e] = V4[h] @ A[l]
        const int e = t, h = e >> 4, l = e & 15;
        const float* v4 = ws + OFF_V4 + h * 16;
        const float* Am = ws + OFF_A + l * 256;
        float outv[R];
        #pragma unroll
        for (int s2 = 0; s2 < R; s2++) outv[s2] = 0.f;
        #pragma unroll
        for (int k = 0; k < R; k++) {
            const float a = v4[k];
            #pragma unroll
            for (int s2 = 0; s2 < R; s2++) outv[s2] += a * Am[k * 16 + s2];
        }
        float* o = ws + OFF_V8 + e * 16;
        #pragma unroll
        for (int s2 = 0; s2 < R; s2++) o[s2] = outv[s2];
    } else { // g == 33: W8[e] = F[h] @ W4[l]
        const int e = t, h = e >> 4, l = e & 15;
        const float* Fm = ws + OFF_F + h * 256;
        const float* w4 = ws + OFF_W4 + l * 16;
        float outv[R];
        #pragma unroll
        for (int r2 = 0; r2 < R; r2++) {
            float acc = 0.f;
            #pragma unroll
            for (int k = 0; k < R; k++) acc += Fm[r2 * 16 + k] * w4[k];
            outv[r2] = acc;
        }
        float* o = ws + OFF_W8 + e * 16;
        #pragma unroll
        for (int r2 = 0; r2 < R; r2++) o[r2] = outv[r2];
    }
}

// ---------------------------------------------------------------------------
// Kernel C: final 16-bit tables. blocks 0..255: prefix (block = hi8, thread =
// lo8); blocks 256..511: suffix (block = hi8, thread = lo8). Contiguous 16 KB
// writes per block.
__global__ __launch_bounds__(256) void tt_final(float* __restrict__ ws) {
    const int t = threadIdx.x;
    if (blockIdx.x < 256) {
        const int h = blockIdx.x, l = t;
        __shared__ float sv[16];
        if (t < 16) sv[t] = ws[OFF_V8 + h * 16 + t];
        __syncthreads();
        const float* P = ws + OFF_P8 + l * 256;
        float outv[R];
        #pragma unroll
        for (int s2 = 0; s2 < R; s2++) outv[s2] = 0.f;
        #pragma unroll
        for (int r2 = 0; r2 < R; r2++) {
            const float a = sv[r2];
            #pragma unroll
            for (int s2 = 0; s2 < R; s2++) outv[s2] += a * P[r2 * 16 + s2];
        }
        float* o = ws + OFF_V16 + (size_t)(h * 256 + l) * 16;
        #pragma unroll
        for (int s2 = 0; s2 < R; s2++) o[s2] = outv[s2];
    } else {
        const int h = blockIdx.x - 256, l = t;
        __shared__ float sQ[256];
        sQ[t] = ws[OFF_Q8 + h * 256 + t];
        __syncthreads();
        const float* wv = ws + OFF_W8 + l * 16;
        float w[R];
        #pragma unroll
        for (int k = 0; k < R; k++) w[k] = wv[k];
        float outv[R];
        #pragma unroll
        for (int r2 = 0; r2 < R; r2++) {
            float acc = 0.f;
            #pragma unroll
            for (int k = 0; k < R; k++) acc += sQ[r2 * 16 + k] * w[k];
            outv[r2] = acc;
        }
        float* o = ws + OFF_W16 + (size_t)(h * 256 + l) * 16;
        #pragma unroll
        for (int r2 = 0; r2 < R; r2++) o[r2] = outv[r2];
    }
}

// ---------------------------------------------------------------------------
// Kernel D: main. One thread per batch element: read 32 bits, two 64 B
// gathers, 16-wide dot.
__global__ __launch_bounds__(256) void tt_main(const int* __restrict__ X,
                                               const float* __restrict__ ws,
                                               float* __restrict__ out) {
    const int b = blockIdx.x * 256 + threadIdx.x;
    const int4* Xr = (const int4*)(X + (size_t)b * TT_D);
    int xv[TT_D];
    #pragma unroll
    for (int q = 0; q < 8; q++) {
        int4 c = Xr[q];
        xv[q * 4 + 0] = c.x; xv[q * 4 + 1] = c.y; xv[q * 4 + 2] = c.z; xv[q * 4 + 3] = c.w;
    }
    unsigned p = 0, s = 0;
    #pragma unroll
    for (int i = 0; i < 16; i++) p = (p << 1) | (unsigned)(xv[i] & 1);
    #pragma unroll
    for (int i = 16; i < 32; i++) s = (s << 1) | (unsigned)(xv[i] & 1);

    const float4* v = (const float4*)(ws + OFF_V16 + (size_t)p * 16);
    const float4* w = (const float4*)(ws + OFF_W16 + (size_t)s * 16);
    float acc = 0.f;
    #pragma unroll
    for (int k = 0; k < 4; k++) {
        float4 a = v[k], c = w[k];
        acc += a.x * c.x + a.y * c.y + a.z * c.z + a.w * c.w;
    }
    out[b] = acc;
}

// ---------------------------------------------------------------------------
// Fallback: direct per-thread chain (used only if ws too small). Correct but
// slow (~LDS-bound).
__global__ __launch_bounds__(256) void tt_direct(const int* __restrict__ X,
                                                 const float* __restrict__ cf,
                                                 const float* __restrict__ cm,
                                                 const float* __restrict__ cl,
                                                 float* __restrict__ out) {
    __shared__ float scm[30 * 16 * 16 * 2];
    for (int i = threadIdx.x; i < 30 * 16 * 16 * 2; i += blockDim.x) scm[i] = cm[i];
    __syncthreads();
    const int b = blockIdx.x * blockDim.x + threadIdx.x;
    if (b >= BATCH) return;
    const int* xr = X + (size_t)b * TT_D;
    float v[R], nv[R];
    const int x0 = xr[0] & 1;
    #pragma unroll
    for (int r = 0; r < R; r++) v[r] = cf[r * 2 + x0];
    for (int i = 1; i <= 30; i++) {
        const int bit = xr[i] & 1;
        const float* M = scm + (i - 1) * 512;
        #pragma unroll
        for (int s2 = 0; s2 < R; s2++) {
            float acc = 0.f;
            #pragma unroll
            for (int r = 0; r < R; r++) acc += v[r] * M[(r * 16 + s2) * 2 + bit];
            nv[s2] = acc;
        }
        #pragma unroll
        for (int s2 = 0; s2 < R; s2++) v[s2] = nv[s2];
    }
    const int xl = xr[31] & 1;
    float acc = 0.f;
    #pragma unroll
    for (int r = 0; r < R; r++) acc += v[r] * cl[r * 2 + xl];
    out[b] = acc;
}

extern "C" void kernel_launch(void* const* d_in, const int* in_sizes, int n_in,
                              void* d_out, int out_size, void* d_ws, size_t ws_size,
                              hipStream_t stream) {
    const int* X = (const int*)d_in[0];
    const float* cf = (const float*)d_in[1];
    const float* cm = (const float*)d_in[2];
    const float* cl = (const float*)d_in[3];
    float* out = (float*)d_out;

    if (ws_size >= (size_t)WS_FLOATS * sizeof(float)) {
        float* ws = (float*)d_ws;
        tt_nibble<<<8, 256, 0, stream>>>(cf, cm, cl, ws);
        tt_byte<<<34, 256, 0, stream>>>(ws);
        tt_final<<<512, 256, 0, stream>>>(ws);
        tt_main<<<BATCH / 256, 256, 0, stream>>>(X, ws, out);
    } else {
        tt_direct<<<(BATCH + 255) / 256, 256, 0, stream>>>(X, cf, cm, cl, out);
    }
}